// Round 1
// baseline (315.169 us; speedup 1.0000x reference)
//
#include <hip/hip_runtime.h>
#include <hip/hip_bf16.h>
#include <stdint.h>

// ---------------------------------------------------------------------------
// ChebConv with attention + per-(t,k) dropout, MI355X bf16 MFMA implementation
// out[b,t,u,o] = relu( sum_k M[t,k] @ (x[b,t] @ Theta[k]) ),
// M[t,k,u,v] = mask(t,k,u,v) ? cheb[k,u,v]*Att[u,v]/0.4 : 0
// mask = jax.random.bernoulli(key(42), 0.4, (T,K,V,V))  -- threefry2x32
// B=32 T=12 V=1000(pad 1024) F=O=64 K=3
// ws layout: M bf16 [36][1024][1024] (75.5MB) | xt bf16 [12][2048][1024] (50.3MB)
// total ws needed: 125,829,120 bytes
// ---------------------------------------------------------------------------

typedef __attribute__((ext_vector_type(8))) short short8;
typedef __attribute__((ext_vector_type(4))) float f32x4;

#define MASK_VARIANT 0
// 0: partitionable, bits = x0 ^ x1   (modern JAX default -- best guess)
// 1: partitionable, bits = x1 (low word)
// 2: partitionable, bits = x0 (high word)
// 3: legacy (threefry_partitionable=False), paired iota halves

__device__ __forceinline__ ushort f2bf(float f) {
  __hip_bfloat16 h = __float2bfloat16(f);
  return *reinterpret_cast<ushort*>(&h);
}

__device__ __forceinline__ void threefry2x32(uint32_t c0, uint32_t c1,
                                             uint32_t& o0, uint32_t& o1) {
  const uint32_t ks0 = 0u;                       // key hi word of seed 42
  const uint32_t ks1 = 42u;                      // key lo word
  const uint32_t ks2 = ks0 ^ ks1 ^ 0x1BD11BDAu;
  uint32_t x0 = c0 + ks0;
  uint32_t x1 = c1 + ks1;
#define TFR(r) { x0 += x1; x1 = (x1 << (r)) | (x1 >> (32 - (r))); x1 ^= x0; }
  TFR(13) TFR(15) TFR(26) TFR(6)
  x0 += ks1; x1 += ks2 + 1u;
  TFR(17) TFR(29) TFR(16) TFR(24)
  x0 += ks2; x1 += ks0 + 2u;
  TFR(13) TFR(15) TFR(26) TFR(6)
  x0 += ks0; x1 += ks1 + 3u;
  TFR(17) TFR(29) TFR(16) TFR(24)
  x0 += ks1; x1 += ks2 + 4u;
  TFR(13) TFR(15) TFR(26) TFR(6)
  x0 += ks2; x1 += ks0 + 5u;
#undef TFR
  o0 = x0; o1 = x1;
}

// ---------------------------------------------------------------------------
// Kernel 1: build masked M (bf16) into ws, padded [36][1024][1024].
// One thread per padded element; padded lanes write 0.
// ---------------------------------------------------------------------------
__global__ void build_m(const float* __restrict__ Att,
                        const float* __restrict__ cheb,
                        ushort* __restrict__ Mws) {
  const uint32_t idx = blockIdx.x * 256u + threadIdx.x;  // < 36*1024*1024
  const uint32_t vp = idx & 1023u;
  const uint32_t up = (idx >> 10) & 1023u;
  const uint32_t tk = idx >> 20;                          // t*3+k, < 36
  float val = 0.f;
  if ((vp < 1000u) & (up < 1000u)) {
    const uint32_t flat = (tk * 1000u + up) * 1000u + vp; // row-major (T,K,V,V)
    uint32_t o0, o1, bits;
#if MASK_VARIANT == 3
    if (flat < 18000000u) { threefry2x32(flat, flat + 18000000u, o0, o1); bits = o0; }
    else                  { threefry2x32(flat - 18000000u, flat, o0, o1); bits = o1; }
#else
    threefry2x32(0u, flat, o0, o1);   // counter = u64 flat index: (hi=0, lo=flat)
#if MASK_VARIANT == 0
    bits = o0 ^ o1;
#elif MASK_VARIANT == 1
    bits = o1;
#else
    bits = o0;
#endif
#endif
    const float u = __uint_as_float((bits >> 9) | 0x3f800000u) - 1.0f;
    if (u < 0.4f) {  // keep (bernoulli p = 1 - 0.6)
      val = cheb[(tk % 3u) * 1000000u + up * 1000u + vp] *
            Att[up * 1000u + vp] * 2.5f;  // / keep
    }
  }
  Mws[idx] = f2bf(val);  // padded layout offset == idx
}

// ---------------------------------------------------------------------------
// Kernel 2: xt[t][n=b*64+f][v(1024 pad)] bf16  <-  x[b][t][v][f] f32
// Per block: one (b,t,64-v-chunk): coalesced f32 read, LDS transpose, 16B writes
// ---------------------------------------------------------------------------
__global__ void transpose_x(const float* __restrict__ x,
                            ushort* __restrict__ xt) {
  __shared__ float lt[64][65];
  const int vc = blockIdx.x, t = blockIdx.y, b = blockIdx.z;
  const int tid = threadIdx.x;
  const int v0 = vc * 64;
#pragma unroll
  for (int i = 0; i < 4; ++i) {
    const int c = i * 256 + tid;       // 0..1023
    const int vi = c >> 4, f4 = c & 15;
    float4 q = make_float4(0.f, 0.f, 0.f, 0.f);
    if (v0 + vi < 1000)
      q = *(const float4*)(x + ((((size_t)b * 12 + t) * 1000 + v0 + vi) << 6) + f4 * 4);
    lt[f4 * 4 + 0][vi] = q.x;
    lt[f4 * 4 + 1][vi] = q.y;
    lt[f4 * 4 + 2][vi] = q.z;
    lt[f4 * 4 + 3][vi] = q.w;
  }
  __syncthreads();
  const int f = tid >> 2, g = tid & 3;  // f-row, 16-v segment
  alignas(16) ushort tmp[16];
#pragma unroll
  for (int j = 0; j < 16; ++j) tmp[j] = f2bf(lt[f][g * 16 + j]);
  const size_t base = ((size_t)(t * 2048 + b * 64 + f)) << 10;
  *(uint4*)(xt + base + v0 + g * 16)     = *(const uint4*)&tmp[0];
  *(uint4*)(xt + base + v0 + g * 16 + 8) = *(const uint4*)&tmp[8];
}

// ---------------------------------------------------------------------------
// Kernel 3: main fused GEMM.
// Block = (t, 128 u-rows, 128 n-cols) where n = b_local*64 + f (2 batches).
// For each k: P = M[t,k,utile,:] @ xt[t,:,ntile]  (K=1024, MFMA 16x16x32),
//             P -> bf16 -> wave-local LDS, out += P @ ThetaT[k].
// Epilogue: relu + store f32.
// ---------------------------------------------------------------------------
#define LDP 72  // padded LDS row length (elements) -> kills stride-128B conflicts

__device__ __forceinline__ f32x4 mfma_bf16(short8 a, short8 b, f32x4 c) {
  asm volatile("v_mfma_f32_16x16x32_bf16 %0, %1, %2, %0"
               : "+v"(c) : "v"(a), "v"(b));
  return c;
}

__global__ __launch_bounds__(256, 2)
void cheb_main(const ushort* __restrict__ Mws, const ushort* __restrict__ xt,
               const float* __restrict__ Theta, float* __restrict__ out) {
  __shared__ ushort sAB[2 * 128 * LDP];  // A tile | B tile; P overlays after barrier
  __shared__ ushort sTh[3 * 64 * LDP];   // ThetaT[k][o][f] bf16

  const int tid = threadIdx.x;
  const int lane = tid & 63;
  const int w = tid >> 6;          // wave 0..3
  const int wu = w >> 1, wn = w & 1;
  const int quad = lane >> 4, l15 = lane & 15;
  const int nt = blockIdx.x, ut = blockIdx.y, t = blockIdx.z;
  const int u0 = ut * 128, n0 = nt * 128;

  // stage Theta^T (once): sTh[k][o][f] = Theta[k][f][o]
  for (int e = tid; e < 3 * 64 * 64; e += 256) {
    const int kk = e >> 12, rem = e & 4095, f = rem >> 6, o = rem & 63;
    sTh[kk * (64 * LDP) + o * LDP + f] = f2bf(Theta[e]);
  }

  f32x4 oacc[4][4];
#pragma unroll
  for (int i = 0; i < 4; ++i)
#pragma unroll
    for (int j = 0; j < 4; ++j) oacc[i][j] = f32x4{0.f, 0.f, 0.f, 0.f};

  ushort* sA = sAB;
  ushort* sB = sAB + 128 * LDP;
  ushort* sP = sAB + w * (64 * LDP);  // wave-local 64x72 region (reuses A/B space)

  for (int kk = 0; kk < 3; ++kk) {
    f32x4 pacc[4][4];
#pragma unroll
    for (int i = 0; i < 4; ++i)
#pragma unroll
      for (int j = 0; j < 4; ++j) pacc[i][j] = f32x4{0.f, 0.f, 0.f, 0.f};

    const size_t mbase = (size_t)(t * 3 + kk) << 20;  // elements

    for (int vc = 0; vc < 16; ++vc) {
      __syncthreads();  // previous readers (frags / stage2 P) done
      // ---- stage A (M rows) and B (xt rows), 16B per thread-chunk ----
#pragma unroll
      for (int i = 0; i < 4; ++i) {
        const int c = i * 256 + tid;
        const int row = c >> 3, seg = c & 7;
        const int col = vc * 64 + seg * 8;
        const uint4 va = *(const uint4*)(Mws + mbase + ((size_t)(u0 + row) << 10) + col);
        *(uint4*)&sA[row * LDP + seg * 8] = va;
        const uint4 vb = *(const uint4*)(xt + (((size_t)(t * 2048 + n0 + row)) << 10) + col);
        *(uint4*)&sB[row * LDP + seg * 8] = vb;
      }
      __syncthreads();
      // ---- MFMA over this 64-wide v chunk ----
#pragma unroll
      for (int ks = 0; ks < 2; ++ks) {
        short8 av[4], bv[4];
#pragma unroll
        for (int mi = 0; mi < 4; ++mi)
          av[mi] = *(const short8*)&sA[(wu * 64 + mi * 16 + l15) * LDP + ks * 32 + quad * 8];
#pragma unroll
        for (int ni = 0; ni < 4; ++ni)
          bv[ni] = *(const short8*)&sB[(wn * 64 + ni * 16 + l15) * LDP + ks * 32 + quad * 8];
#pragma unroll
        for (int mi = 0; mi < 4; ++mi)
#pragma unroll
          for (int ni = 0; ni < 4; ++ni)
            pacc[mi][ni] = mfma_bf16(av[mi], bv[ni], pacc[mi][ni]);
      }
    }

    // ---- stage 2: out += P @ Theta_k^T ----
    __syncthreads();  // all waves done reading sA/sB before P overlays them
#pragma unroll
    for (int mi = 0; mi < 4; ++mi)
#pragma unroll
      for (int ni = 0; ni < 4; ++ni)
#pragma unroll
        for (int r = 0; r < 4; ++r)
          sP[(mi * 16 + quad * 4 + r) * LDP + ni * 16 + l15] = f2bf(pacc[mi][ni][r]);
    __syncthreads();
#pragma unroll
    for (int ks = 0; ks < 2; ++ks) {
      short8 a2[4], b2[4];
#pragma unroll
      for (int mi = 0; mi < 4; ++mi)
        a2[mi] = *(const short8*)&sP[(mi * 16 + l15) * LDP + ks * 32 + quad * 8];
#pragma unroll
      for (int ni = 0; ni < 4; ++ni)
        b2[ni] = *(const short8*)&sTh[kk * (64 * LDP) + (ni * 16 + l15) * LDP + ks * 32 + quad * 8];
#pragma unroll
      for (int mi = 0; mi < 4; ++mi)
#pragma unroll
        for (int ni = 0; ni < 4; ++ni)
          oacc[mi][ni] = mfma_bf16(a2[mi], b2[ni], oacc[mi][ni]);
    }
    // loop-top __syncthreads protects sP before next k's A/B staging
  }

  // ---- epilogue: relu + store ----
#pragma unroll
  for (int mi = 0; mi < 4; ++mi) {
    const int u_base = u0 + wu * 64 + mi * 16 + quad * 4;
#pragma unroll
    for (int ni = 0; ni < 4; ++ni) {
      const int n = n0 + wn * 64 + ni * 16 + l15;
      const int b = n >> 6, oo = n & 63;
      float* op = out + (((size_t)b * 12 + t) * 1000) * 64 + oo;
#pragma unroll
      for (int r = 0; r < 4; ++r) {
        const int u = u_base + r;
        if (u < 1000) op[(size_t)u * 64] = fmaxf(oacc[mi][ni][r], 0.f);
      }
    }
  }
}

// ---------------------------------------------------------------------------
extern "C" void kernel_launch(void* const* d_in, const int* in_sizes, int n_in,
                              void* d_out, int out_size, void* d_ws, size_t ws_size,
                              hipStream_t stream) {
  const float* x     = (const float*)d_in[0];  // [32,12,1000,64]
  const float* Att   = (const float*)d_in[1];  // [1000,1000]
  const float* cheb  = (const float*)d_in[2];  // [3,1000,1000]
  const float* Theta = (const float*)d_in[3];  // [3,64,64]
  float* out = (float*)d_out;                  // [32,12,1000,64]

  ushort* Mws = (ushort*)d_ws;                 // 36*1024*1024 bf16 = 75.5 MB
  ushort* xtw = Mws + 37748736ull;             // 12*2048*1024 bf16 = 50.3 MB
  // requires ws_size >= 125,829,120 bytes

  build_m<<<147456, 256, 0, stream>>>(Att, cheb, Mws);
  transpose_x<<<dim3(16, 12, 32), 256, 0, stream>>>(x, xtw);
  cheb_main<<<dim3(16, 8, 12), 256, 0, stream>>>(Mws, xtw, Theta, out);
}

// Round 3
// 310.664 us; speedup vs baseline: 1.0145x; 1.0145x over previous
//
#include <hip/hip_runtime.h>
#include <hip/hip_bf16.h>
#include <stdint.h>

// ---------------------------------------------------------------------------
// ChebConv with attention + per-(t,k) dropout, MI355X bf16 MFMA implementation
// out[b,t,u,o] = relu( sum_k M[t,k] @ (x[b,t] @ Theta[k]) )
// M[t,k,u,v] = mask(t,k,u,v) ? cheb[k,u,v]*Att[u,v]/0.4 : 0
// mask = threefry2x32 partitionable, key(42), bits = x0^x1   (verified R0)
// B=32 T=12 V=1000(pad 1024) F=O=64 K=3
// ws: M bf16 [36][1024][1024] (75.5MB) | xt bf16 [12][2048][1024] (50.3MB)
//
// R3: same geometry/swizzle as R2 but staging via explicit uint4 load +
// ds_write (R1-proven path) instead of global_load_lds -- isolates R2's
// failure to the gl_lds usage while keeping occupancy + conflict fixes.
// ---------------------------------------------------------------------------

typedef __attribute__((ext_vector_type(8))) short short8;
typedef __attribute__((ext_vector_type(4))) float f32x4;

__device__ __forceinline__ ushort f2bf(float f) {
  __hip_bfloat16 h = __float2bfloat16(f);
  return *reinterpret_cast<ushort*>(&h);
}

__device__ __forceinline__ void threefry2x32(uint32_t c0, uint32_t c1,
                                             uint32_t& o0, uint32_t& o1) {
  const uint32_t ks0 = 0u;
  const uint32_t ks1 = 42u;
  const uint32_t ks2 = ks0 ^ ks1 ^ 0x1BD11BDAu;
  uint32_t x0 = c0 + ks0;
  uint32_t x1 = c1 + ks1;
#define TFR(r) { x0 += x1; x1 = (x1 << (r)) | (x1 >> (32 - (r))); x1 ^= x0; }
  TFR(13) TFR(15) TFR(26) TFR(6)
  x0 += ks1; x1 += ks2 + 1u;
  TFR(17) TFR(29) TFR(16) TFR(24)
  x0 += ks2; x1 += ks0 + 2u;
  TFR(13) TFR(15) TFR(26) TFR(6)
  x0 += ks0; x1 += ks1 + 3u;
  TFR(17) TFR(29) TFR(16) TFR(24)
  x0 += ks1; x1 += ks2 + 4u;
  TFR(13) TFR(15) TFR(26) TFR(6)
  x0 += ks2; x1 += ks0 + 5u;
#undef TFR
  o0 = x0; o1 = x1;
}

// ---------------------------------------------------------------------------
// Kernel 1: build masked M (bf16) into ws, padded [36][1024][1024].
// ---------------------------------------------------------------------------
__global__ void build_m(const float* __restrict__ Att,
                        const float* __restrict__ cheb,
                        ushort* __restrict__ Mws) {
  const uint32_t idx = blockIdx.x * 256u + threadIdx.x;
  const uint32_t vp = idx & 1023u;
  const uint32_t up = (idx >> 10) & 1023u;
  const uint32_t tk = idx >> 20;
  float val = 0.f;
  if ((vp < 1000u) & (up < 1000u)) {
    const uint32_t flat = (tk * 1000u + up) * 1000u + vp;
    uint32_t o0, o1;
    threefry2x32(0u, flat, o0, o1);
    const uint32_t bits = o0 ^ o1;
    const float u = __uint_as_float((bits >> 9) | 0x3f800000u) - 1.0f;
    if (u < 0.4f) {
      val = cheb[(tk % 3u) * 1000000u + up * 1000u + vp] *
            Att[up * 1000u + vp] * 2.5f;
    }
  }
  Mws[idx] = f2bf(val);
}

// ---------------------------------------------------------------------------
// Kernel 2: xt[t][n=b*64+f][v(1024 pad)] bf16  <-  x[b][t][v][f] f32
// ---------------------------------------------------------------------------
__global__ void transpose_x(const float* __restrict__ x,
                            ushort* __restrict__ xt) {
  __shared__ float lt[64][65];
  const int vc = blockIdx.x, t = blockIdx.y, b = blockIdx.z;
  const int tid = threadIdx.x;
  const int v0 = vc * 64;
#pragma unroll
  for (int i = 0; i < 4; ++i) {
    const int c = i * 256 + tid;
    const int vi = c >> 4, f4 = c & 15;
    float4 q = make_float4(0.f, 0.f, 0.f, 0.f);
    if (v0 + vi < 1000)
      q = *(const float4*)(x + ((((size_t)b * 12 + t) * 1000 + v0 + vi) << 6) + f4 * 4);
    lt[f4 * 4 + 0][vi] = q.x;
    lt[f4 * 4 + 1][vi] = q.y;
    lt[f4 * 4 + 2][vi] = q.z;
    lt[f4 * 4 + 3][vi] = q.w;
  }
  __syncthreads();
  const int f = tid >> 2, g = tid & 3;
  alignas(16) ushort tmp[16];
#pragma unroll
  for (int j = 0; j < 16; ++j) tmp[j] = f2bf(lt[f][g * 16 + j]);
  const size_t base = ((size_t)(t * 2048 + b * 64 + f)) << 10;
  *(uint4*)(xt + base + v0 + g * 16)     = *(const uint4*)&tmp[0];
  *(uint4*)(xt + base + v0 + g * 16 + 8) = *(const uint4*)&tmp[8];
}

// ---------------------------------------------------------------------------
// Kernel 3: main fused GEMM.  Block = 512 thr (8 waves), tile 128(u) x 128(n)
// per t.  Wave tile 32u x 64n.  Per k: P = M[t,k] @ xt (K=1024, 16 chunks of
// 64), P->bf16->wave-local LDS, oacc += P @ ThetaT[k].  Relu + f32 store.
// LDS: sA[128][64] | sB[128][64], lane-linear writes (conflict-free),
//      content XOR-swizzled: LDS[r][chunk c] = G[r][c ^ (r&7)] (16B chunks);
//      read at c = want ^ (r&7)  ->  2 lanes/chunk = free.
//      sP (wave-local 32x72) overlays sA/sB; sTh[64][72] per-k ThetaT.
// ---------------------------------------------------------------------------
#define LDT 72  // padded row (ushorts) for sTh / sP

__device__ __forceinline__ f32x4 mfma_bf16(short8 a, short8 b, f32x4 c) {
  asm volatile("v_mfma_f32_16x16x32_bf16 %0, %1, %2, %0"
               : "+v"(c) : "v"(a), "v"(b));
  return c;
}

__global__ __launch_bounds__(512, 3)
void cheb_main(const ushort* __restrict__ Mws, const ushort* __restrict__ xt,
               const float* __restrict__ Theta, float* __restrict__ out) {
  // sA [0,8192) ushorts, sB [8192,16384); sP union [0, 8*32*72=18432);
  // sTh at 18432, 64*72=4608. Total 23040 ushorts = 46080 B.
  __shared__ __align__(16) ushort smem[23040];
  const int tid = threadIdx.x;
  const int lane = tid & 63;
  const int w = tid >> 6;              // wave 0..7
  const int wu = w >> 1, wn = w & 1;   // wave tile: u = wu*32, n = wn*64
  const int quad = lane >> 4, l15 = lane & 15;
  const int nt = blockIdx.x, ut = blockIdx.y, t = blockIdx.z;
  const int u0 = ut * 128, n0 = nt * 128;

  ushort* sA  = smem;
  ushort* sB  = smem + 8192;
  ushort* sP  = smem + w * (32 * LDT);   // wave-local, overlays sA/sB
  ushort* sTh = smem + 8 * 32 * LDT;     // 18432

  // staging lane geometry: lane covers row srow, dest chunk schunk,
  // source chunk gchunk = schunk ^ srow  (so LDS[r][c] = G[r][c^(r&7)])
  const int srow = lane >> 3;            // 0..7
  const int schunk = lane & 7;
  const int gchunk = schunk ^ srow;
  const int rsw = l15 & 7;               // read-side swizzle key (= row&7)

  f32x4 oacc[2][4];
#pragma unroll
  for (int i = 0; i < 2; ++i)
#pragma unroll
    for (int j = 0; j < 4; ++j) oacc[i][j] = f32x4{0.f, 0.f, 0.f, 0.f};

  for (int kk = 0; kk < 3; ++kk) {
    __syncthreads();  // prev stage2 readers of sP/sTh done
    // stage ThetaT[k]: sTh[o][f] = Theta[k][f][o]
    for (int e = tid; e < 4096; e += 512) {
      const int f = e >> 6, o = e & 63;
      sTh[o * LDT + f] = f2bf(Theta[kk * 4096 + e]);
    }

    f32x4 pacc[2][4];
#pragma unroll
    for (int i = 0; i < 2; ++i)
#pragma unroll
      for (int j = 0; j < 4; ++j) pacc[i][j] = f32x4{0.f, 0.f, 0.f, 0.f};

    const size_t mbase = (size_t)(t * 3 + kk) << 20;
    const size_t xrow0 = (size_t)(t * 2048 + n0);

    for (int vc = 0; vc < 16; ++vc) {
      __syncthreads();  // prev chunk's frag reads (or sP/sTh writes) done
      // ---- stage A(M) and B(xt): explicit uint4 load + lane-linear ds_write
#pragma unroll
      for (int j = 0; j < 2; ++j) {
        const int rr = 8 * (w * 2 + j) + srow;   // tile row 0..127
        const uint4 va = *(const uint4*)(Mws + mbase +
                          ((size_t)(u0 + rr) << 10) + vc * 64 + gchunk * 8);
        *(uint4*)&sA[(w * 2 + j) * 512 + lane * 8] = va;
        const uint4 vb = *(const uint4*)(xt +
                          ((xrow0 + rr) << 10) + vc * 64 + gchunk * 8);
        *(uint4*)&sB[(w * 2 + j) * 512 + lane * 8] = vb;
      }
      __syncthreads();  // tiles ready
      // ---- MFMA over this 64-wide v chunk ----
#pragma unroll
      for (int ks = 0; ks < 2; ++ks) {
        short8 av[2], bv[4];
#pragma unroll
        for (int mi = 0; mi < 2; ++mi) {
          const int row = wu * 32 + mi * 16 + l15;
          const int c = (ks * 4 + quad) ^ rsw;   // swizzled chunk
          av[mi] = *(const short8*)&sA[row * 64 + c * 8];
        }
#pragma unroll
        for (int ni = 0; ni < 4; ++ni) {
          const int row = wn * 64 + ni * 16 + l15;
          const int c = (ks * 4 + quad) ^ rsw;
          bv[ni] = *(const short8*)&sB[row * 64 + c * 8];
        }
#pragma unroll
        for (int mi = 0; mi < 2; ++mi)
#pragma unroll
          for (int ni = 0; ni < 4; ++ni)
            pacc[mi][ni] = mfma_bf16(av[mi], bv[ni], pacc[mi][ni]);
      }
    }

    // ---- stage 2: oacc += P @ ThetaT[k] ----
    __syncthreads();  // all waves' frag reads done before P overlays sA/sB
#pragma unroll
    for (int mi = 0; mi < 2; ++mi)
#pragma unroll
      for (int ni = 0; ni < 4; ++ni)
#pragma unroll
        for (int r = 0; r < 4; ++r)
          sP[(mi * 16 + quad * 4 + r) * LDT + ni * 16 + l15] = f2bf(pacc[mi][ni][r]);
    __syncthreads();
#pragma unroll
    for (int ks = 0; ks < 2; ++ks) {
      short8 a2[2], b2[4];
#pragma unroll
      for (int mi = 0; mi < 2; ++mi)
        a2[mi] = *(const short8*)&sP[(mi * 16 + l15) * LDT + ks * 32 + quad * 8];
#pragma unroll
      for (int ni = 0; ni < 4; ++ni)
        b2[ni] = *(const short8*)&sTh[(ni * 16 + l15) * LDT + ks * 32 + quad * 8];
#pragma unroll
      for (int mi = 0; mi < 2; ++mi)
#pragma unroll
        for (int ni = 0; ni < 4; ++ni)
          oacc[mi][ni] = mfma_bf16(a2[mi], b2[ni], oacc[mi][ni]);
    }
  }

  // ---- epilogue: relu + store ----
#pragma unroll
  for (int mi = 0; mi < 2; ++mi) {
    const int u_base = u0 + wu * 32 + mi * 16 + quad * 4;
#pragma unroll
    for (int ni = 0; ni < 4; ++ni) {
      const int n = n0 + wn * 64 + ni * 16 + l15;
      const int b = n >> 6, oo = n & 63;
      float* op = out + (((size_t)b * 12 + t) * 1000) * 64 + oo;
#pragma unroll
      for (int r = 0; r < 4; ++r) {
        const int u = u_base + r;
        if (u < 1000) op[(size_t)u * 64] = fmaxf(oacc[mi][ni][r], 0.f);
      }
    }
  }
}

// ---------------------------------------------------------------------------
extern "C" void kernel_launch(void* const* d_in, const int* in_sizes, int n_in,
                              void* d_out, int out_size, void* d_ws, size_t ws_size,
                              hipStream_t stream) {
  const float* x     = (const float*)d_in[0];
  const float* Att   = (const float*)d_in[1];
  const float* cheb  = (const float*)d_in[2];
  const float* Theta = (const float*)d_in[3];
  float* out = (float*)d_out;

  ushort* Mws = (ushort*)d_ws;                 // 36*1024*1024 bf16
  ushort* xtw = Mws + 37748736ull;             // 12*2048*1024 bf16
  // requires ws_size >= 125,829,120 bytes

  build_m<<<147456, 256, 0, stream>>>(Att, cheb, Mws);
  transpose_x<<<dim3(16, 12, 32), 256, 0, stream>>>(x, xtw);
  cheb_main<<<dim3(16, 8, 12), 512, 0, stream>>>(Mws, xtw, Theta, out);
}